// Round 12
// baseline (6571.717 us; speedup 1.0000x reference)
//
#include <hip/hip_runtime.h>
#include <hip/hip_bf16.h>

#define EN 256
#define HN 512
#define BN 64
#define TN 512
#define NBLK 16
#define KCAT 1280        // 256 Wih_hi | 512 Whh_hi | 512 Whh_lo
#define NBUF 8
#define SLOTB 65536      // one h slot: 16 regions x 4KB ([prod][64 samp][32 col] bf16)

typedef __attribute__((ext_vector_type(8))) short short8;
typedef __attribute__((ext_vector_type(4))) short short4v;
typedef __attribute__((ext_vector_type(4))) float f32x4;

#define SCOPE __HIP_MEMORY_SCOPE_AGENT
#define MFMA(A, B, C) __builtin_amdgcn_mfma_f32_16x16x32_bf16((A), (B), (C), 0, 0, 0)

__device__ inline short bf_of(float f) {
  __hip_bfloat16 h = __float2bfloat16(f);
  return *reinterpret_cast<short*>(&h);
}
__device__ inline float f_of_bf(short s) {
  __hip_bfloat16 h = *reinterpret_cast<__hip_bfloat16*>(&s);
  return __bfloat162float(h);
}

// ---------- K0: zero h slot 0 (h_0 = 0) and the 16 flags ----------
__global__ __launch_bounds__(256) void zero_kernel(unsigned* hb_u32,
                                                   unsigned* flags) {
  int idx = blockIdx.x * 256 + threadIdx.x;
  for (int i = idx; i < SLOTB / 4; i += 64 * 256)
    __hip_atomic_store(&hb_u32[i], 0u, __ATOMIC_RELAXED, SCOPE);
  if (idx < NBLK)
    __hip_atomic_store(&flags[idx], 0u, __ATOMIC_RELAXED, SCOPE);
}

// ---------- K1: weB[t*64+b][k] = bf16(emb[x[b][t]][k]) ----------
__global__ __launch_bounds__(256) void gather_kernel(
    short* __restrict__ weB, const int* __restrict__ x,
    const float* __restrict__ emb) {
  const int t = blockIdx.x;
  const int tid = threadIdx.x;
  const int b = tid >> 2, q = tid & 3;
  const int row = x[b * TN + t];
  const float4* src = (const float4*)(emb + (size_t)row * EN + q * 64);
  short* dst = weB + ((size_t)(t * 64 + b)) * EN + q * 64;
#pragma unroll
  for (int i = 0; i < 16; i++) {
    float4 v = src[i];
    short4v o = { bf_of(v.x), bf_of(v.y), bf_of(v.z), bf_of(v.w) };
    *(short4v*)(dst + i * 4) = o;
  }
}

// ---------- K2: Wall[grow][kc]: kc<256 Wih_hi | <768 Whh_hi | else Whh_lo --
__global__ __launch_bounds__(256) void prep_w_kernel(
    short* __restrict__ Wall, const float* __restrict__ Wih,
    const float* __restrict__ Whh) {
  int idx = blockIdx.x * 256 + threadIdx.x;
  int grow = idx / KCAT, kc = idx - grow * KCAT;
  float v;
  if (kc < 256) {
    v = Wih[(size_t)grow * EN + kc];
  } else if (kc < 768) {
    v = Whh[(size_t)grow * HN + (kc - 256)];
  } else {
    float f = Whh[(size_t)grow * HN + (kc - 768)];
    v = f - f_of_bf(bf_of(f));
  }
  Wall[idx] = bf_of(v);
}

// ---------- scan: 16 blocks x 512 thr; slack-7 dataflow, LDS-shared h -----
__global__ __launch_bounds__(512, 1) void scan_kernel(
    const short* __restrict__ weB, const short* __restrict__ Wall,
    char* __restrict__ hb, const int* __restrict__ length,
    const float* __restrict__ bih, const float* __restrict__ bhh,
    const float* __restrict__ Wcls, const float* __restrict__ bcls,
    float* __restrict__ part, unsigned* flags, float* __restrict__ out) {
  __shared__ short hls[NBLK * 2048];      // 16 regions x 4KB, XOR-swizzled
  __shared__ float gl[128][66];           // gate rows r = type*32+jj, col = sample
  const int tid = threadIdx.x;
  const int l = tid & 63, w = tid >> 6;   // 8 waves; wave w = row-tile w
  const int bid = blockIdx.x;
  const int j0 = bid * 32;

  // ---- A fragments: wave w -> gate rows [w*16, w*16+16) of this block ----
  short8 aX[8], aHh[16], aLh[16];
  {
    int r = w * 16 + (l & 15);            // 0..127: type = r>>5, jj = r&31
    size_t grow = (size_t)(r >> 5) * HN + j0 + (r & 31);
    const short* wp = Wall + grow * KCAT + 8 * (l >> 4);
#pragma unroll
    for (int kk = 0; kk < 8; kk++)  aX[kk]  = *(const short8*)(wp + kk * 32);
#pragma unroll
    for (int p = 0; p < 16; p++)    aHh[p]  = *(const short8*)(wp + (8 + p) * 32);
#pragma unroll
    for (int p = 0; p < 16; p++)    aLh[p]  = *(const short8*)(wp + 768 + p * 32);
  }

  // ---- nonlin role: thread -> (jj = tid>>4 in [0,32), 4 samples) ----
  const int jj = tid >> 4, bq = tid & 15;
  float bias[4];
  int len4[4];
  float c4[4] = {0.f, 0.f, 0.f, 0.f};
  float fmx4[4] = {-INFINITY, -INFINITY, -INFINITY, -INFINITY};
#pragma unroll
  for (int ty = 0; ty < 4; ty++)
    bias[ty] = bih[ty * HN + j0 + jj] + bhh[ty * HN + j0 + jj];
#pragma unroll
  for (int i = 0; i < 4; i++) len4[i] = length[bq * 4 + i];

  // zero own hls region (h_0 = 0 for p = bid)
  {
    int* hz = (int*)&hls[bid * 2048];
    hz[tid] = 0; hz[tid + 512] = 0;
  }
  __syncthreads();

  // stage assignment: wave w fetches producers (bid+1+w)&15 and (bid+9+w)&15
  const int p1 = (bid + 1 + w) & 15;
  const int p2 = (w <= 6) ? ((bid + 9 + w) & 15) : -1;
  // per-lane stage addressing (linear LDS dest = lane*16; swizzled IC src)
  const int stage_src_off = (l >> 2) * 64 + (((l & 3) ^ ((l >> 3) & 3)) * 16);
  // per-lane consumer read offset within a producer region (shorts)
  const int hoff = (l & 15) * 32 + (((l >> 4) ^ (((l & 15) >> 1) & 3)) * 8);

  for (int t = 0; t < TN; t++) {
    // ---- x side: 4 col-tiles x 8 K-chunks (no h dependency) ----
    f32x4 accH[4], accL[4];
#pragma unroll
    for (int ct = 0; ct < 4; ct++) {
      accH[ct] = f32x4{0.f, 0.f, 0.f, 0.f};
      accL[ct] = f32x4{0.f, 0.f, 0.f, 0.f};
      const short* xr = weB + ((size_t)(t * 64 + ct * 16 + (l & 15))) * EN + 8 * (l >> 4);
#pragma unroll
      for (int kk = 0; kk < 8; kk++) {
        short8 xf = *(const short8*)(xr + kk * 32);
        accH[ct] = MFMA(aX[kk], xf, accH[ct]);
      }
    }

    // ---- stage my producers' h_t slices: IC -> LDS ----
    const char* slotp = hb + (size_t)(t & 7) * SLOTB;
    {
      unsigned want = (unsigned)t;
      while (__hip_atomic_load(&flags[p1], __ATOMIC_RELAXED, SCOPE) < want)
        __builtin_amdgcn_s_sleep(2);
      const char* sp = slotp + p1 * 4096 + stage_src_off;
      short8 s0, s1, s2, s3;
      asm volatile(
        "global_load_dwordx4 %0, %4, off sc1\n\t"
        "global_load_dwordx4 %1, %4, off offset:1024 sc1\n\t"
        "global_load_dwordx4 %2, %4, off offset:2048 sc1\n\t"
        "global_load_dwordx4 %3, %4, off offset:3072 sc1\n\t"
        "s_waitcnt vmcnt(0)"
        : "=&v"(s0), "=&v"(s1), "=&v"(s2), "=&v"(s3)
        : "v"(sp) : "memory");
      short* dst = &hls[p1 * 2048 + l * 8];
      *(short8*)(dst)        = s0;
      *(short8*)(dst + 512)  = s1;
      *(short8*)(dst + 1024) = s2;
      *(short8*)(dst + 1536) = s3;
      if (p2 >= 0) {
        while (__hip_atomic_load(&flags[p2], __ATOMIC_RELAXED, SCOPE) < want)
          __builtin_amdgcn_s_sleep(2);
        const char* sq = slotp + p2 * 4096 + stage_src_off;
        asm volatile(
          "global_load_dwordx4 %0, %4, off sc1\n\t"
          "global_load_dwordx4 %1, %4, off offset:1024 sc1\n\t"
          "global_load_dwordx4 %2, %4, off offset:2048 sc1\n\t"
          "global_load_dwordx4 %3, %4, off offset:3072 sc1\n\t"
          "s_waitcnt vmcnt(0)"
          : "=&v"(s0), "=&v"(s1), "=&v"(s2), "=&v"(s3)
          : "v"(sq) : "memory");
        short* dst2 = &hls[p2 * 2048 + l * 8];
        *(short8*)(dst2)        = s0;
        *(short8*)(dst2 + 512)  = s1;
        *(short8*)(dst2 + 1024) = s2;
        *(short8*)(dst2 + 1536) = s3;
      }
    }
    __syncthreads();                      // (s) all h_t staged in LDS

    // ---- h side: 16 producers x 4 col-tiles, hi + lo chains ----
#pragma unroll
    for (int p = 0; p < 16; p++) {
#pragma unroll
      for (int ct = 0; ct < 4; ct++) {
        short8 hv = *(const short8*)&hls[p * 2048 + ct * 512 + hoff];
        accH[ct] = MFMA(aHh[p], hv, accH[ct]);
        accL[ct] = MFMA(aLh[p], hv, accL[ct]);
      }
    }

#pragma unroll
    for (int ct = 0; ct < 4; ct++) {
#pragma unroll
      for (int q = 0; q < 4; q++) {       // C/D: col = lane&15, row = (lane>>4)*4+q
        int r = w * 16 + (l >> 4) * 4 + q;
        gl[r][ct * 16 + (l & 15)] = accH[ct][q] + accL[ct][q];
      }
    }
    __syncthreads();                      // (a) gates ready

    // ---- nonlinearity: thread (jj, 4 samples) ----
#pragma unroll
    for (int i = 0; i < 4; i++) {
      int b = bq * 4 + i;
      float gi = gl[0 * 32 + jj][b] + bias[0];
      float gf = gl[1 * 32 + jj][b] + bias[1];
      float gg = gl[2 * 32 + jj][b] + bias[2];
      float go = gl[3 * 32 + jj][b] + bias[3];
      float si = 1.f / (1.f + __expf(-gi));
      float sf = 1.f / (1.f + __expf(-gf));
      float so = 1.f / (1.f + __expf(-go));
      float tg = 2.f / (1.f + __expf(-2.f * gg)) - 1.f;
      c4[i] = sf * c4[i] + si * tg;
      float tc = 2.f / (1.f + __expf(-2.f * c4[i])) - 1.f;
      float h = so * tc;
      // own region, swizzled: phys chunk = (jj>>3) ^ ((b>>1)&3)
      hls[bid * 2048 + b * 32 + (((jj >> 3) ^ ((b >> 1) & 3)) * 8) + (jj & 7)] = bf_of(h);
      if (t < len4[i]) fmx4[i] = fmaxf(fmx4[i], h);
    }
    __syncthreads();                      // (b) h_{t+1} complete in hls[bid]

    // ---- wave 0 publishes h_{t+1} to IC slot (t+1)&7 + flag ----
    if (w == 0) {
      char* dp = hb + (size_t)((t + 1) & 7) * SLOTB + bid * 4096 + l * 64;
      const int sw = (l >> 1) & 3;
#pragma unroll
      for (int j = 0; j < 4; j++) {
        short8 v = *(const short8*)&hls[bid * 2048 + l * 32 + ((j ^ sw) * 8)];
        asm volatile("global_store_dwordx4 %0, %1, off sc1"
                     :: "v"(dp + j * 16), "v"(v) : "memory");
      }
      asm volatile("s_waitcnt vmcnt(0)" ::: "memory");
      if (l == 0)
        __hip_atomic_store(&flags[bid], (unsigned)(t + 1),
                           __ATOMIC_RELAXED, SCOPE);
    }
    // WAR: writing slot (t+1)&7 clobbers h_{t-7}; our stage(t) verified all
    // flags >= t => every block passed step t-1 => consumed h_{t-7}. Safe.
  }

  // ---- classifier partials over this block's 32 cols ----
  __syncthreads();
#pragma unroll
  for (int i = 0; i < 4; i++) {
    int b = bq * 4 + i;
    gl[0 * 32 + jj][b] = fmx4[i] * Wcls[j0 + jj];
    gl[1 * 32 + jj][b] = fmx4[i] * Wcls[HN + j0 + jj];
  }
  __syncthreads();
  if (tid < 128) {
    int cls = tid >> 6, b = tid & 63;
    float s = 0.f;
#pragma unroll
    for (int q = 0; q < 32; q++) s += gl[cls * 32 + q][b];
    __hip_atomic_store(&part[(size_t)bid * 128 + cls * 64 + b], s,
                       __ATOMIC_RELAXED, SCOPE);
  }
  asm volatile("s_waitcnt vmcnt(0)" ::: "memory");
  __syncthreads();
  if (tid == 0)
    __hip_atomic_store(&flags[bid], (unsigned)(TN + 1), __ATOMIC_RELAXED, SCOPE);
  if (bid == 0) {
    if (w == 0) {
      while (true) {
        unsigned v = __hip_atomic_load(&flags[l & 15], __ATOMIC_RELAXED, SCOPE);
        if (__all(v >= (unsigned)(TN + 1))) break;
        __builtin_amdgcn_s_sleep(2);
      }
      asm volatile("" ::: "memory");
    }
    __syncthreads();
    if (tid < 128) {
      int cls = tid >> 6, b = tid & 63;
      float s = bcls[cls];
#pragma unroll
      for (int k = 0; k < NBLK; k++)
        s += __uint_as_float(__hip_atomic_load(
            (const unsigned*)&part[(size_t)k * 128 + cls * 64 + b],
            __ATOMIC_RELAXED, SCOPE));
      out[b * 2 + cls] = s;
    }
  }
}

extern "C" void kernel_launch(void* const* d_in, const int* in_sizes, int n_in,
                              void* d_out, int out_size, void* d_ws, size_t ws_size,
                              hipStream_t stream) {
  const int*   x    = (const int*)d_in[0];
  const int*   len  = (const int*)d_in[1];
  const float* emb  = (const float*)d_in[2];
  const float* Wih  = (const float*)d_in[3];
  const float* Whh  = (const float*)d_in[4];
  const float* bih  = (const float*)d_in[5];
  const float* bhh  = (const float*)d_in[6];
  const float* Wcls = (const float*)d_in[7];
  const float* bcls = (const float*)d_in[8];
  float* out = (float*)d_out;

  char* ws = (char*)d_ws;
  short* weB  = (short*)ws;                                   // 16,777,216 B
  short* Wall = (short*)(ws + 16777216ull);                   //  5,242,880 B
  char*  hb   = ws + 16777216ull + 5242880;                   // 8*64KB = 524,288 B
  float* part = (float*)(ws + 16777216ull + 5242880 + 524288);          // 8 KB
  unsigned* flagp = (unsigned*)(ws + 16777216ull + 5242880 + 524288 + 8192);

  zero_kernel<<<dim3(64), dim3(256), 0, stream>>>((unsigned*)hb, flagp);
  gather_kernel<<<dim3(TN), dim3(256), 0, stream>>>(weB, x, emb);
  prep_w_kernel<<<dim3((2048 * KCAT) / 256), dim3(256), 0, stream>>>(Wall, Wih, Whh);

  void* args[] = { (void*)&weB, (void*)&Wall, (void*)&hb, (void*)&len,
                   (void*)&bih, (void*)&bhh, (void*)&Wcls, (void*)&bcls,
                   (void*)&part, (void*)&flagp, (void*)&out };
  hipLaunchCooperativeKernel((void*)scan_kernel, dim3(NBLK), dim3(512),
                             args, 0, stream);
}

// Round 13
// 2348.422 us; speedup vs baseline: 2.7984x; 2.7984x over previous
//
#include <hip/hip_runtime.h>
#include <hip/hip_bf16.h>

#define EN 256
#define HN 512
#define BN 64
#define TN 512
#define NBLK 64
#define KCAT 1280        // 256 Wih_hi | 512 Whh_hi | 512 Whh_lo
#define NBUF 8
#define SLOTB 65536      // one h slot: [(p&3)][p>>2][64 samples][8 cols] bf16

typedef __attribute__((ext_vector_type(8))) short short8;
typedef __attribute__((ext_vector_type(4))) short short4v;
typedef __attribute__((ext_vector_type(4))) float f32x4;

#define SCOPE __HIP_MEMORY_SCOPE_AGENT
#define MFMA(A, B, C) __builtin_amdgcn_mfma_f32_16x16x32_bf16((A), (B), (C), 0, 0, 0)

__device__ inline short bf_of(float f) {
  __hip_bfloat16 h = __float2bfloat16(f);
  return *reinterpret_cast<short*>(&h);
}
__device__ inline float f_of_bf(short s) {
  __hip_bfloat16 h = *reinterpret_cast<__hip_bfloat16*>(&s);
  return __bfloat162float(h);
}

// ---------- K0: zero h slot 0 (h_0 = 0) and flags ----------
__global__ __launch_bounds__(256) void zero_kernel(unsigned* hb_u32,
                                                   unsigned* flags) {
  int idx = blockIdx.x * 256 + threadIdx.x;
  if (idx < SLOTB / 4)
    __hip_atomic_store(&hb_u32[idx], 0u, __ATOMIC_RELAXED, SCOPE);
  if (idx < NBLK)
    __hip_atomic_store(&flags[idx], 0u, __ATOMIC_RELAXED, SCOPE);
}

// ---------- K1: weB[t*64+b][k] = bf16(emb[x[b][t]][k]) ----------
__global__ __launch_bounds__(256) void gather_kernel(
    short* __restrict__ weB, const int* __restrict__ x,
    const float* __restrict__ emb) {
  const int t = blockIdx.x;
  const int tid = threadIdx.x;
  const int b = tid >> 2, q = tid & 3;
  const int row = x[b * TN + t];
  const float4* src = (const float4*)(emb + (size_t)row * EN + q * 64);
  short* dst = weB + ((size_t)(t * 64 + b)) * EN + q * 64;
#pragma unroll
  for (int i = 0; i < 16; i++) {
    float4 v = src[i];
    short4v o = { bf_of(v.x), bf_of(v.y), bf_of(v.z), bf_of(v.w) };
    *(short4v*)(dst + i * 4) = o;
  }
}

// ---------- K2: Wall[grow][kc]: kc<256 Wih_hi | <768 Whh_hi | else Whh_lo --
__global__ __launch_bounds__(256) void prep_w_kernel(
    short* __restrict__ Wall, const float* __restrict__ Wih,
    const float* __restrict__ Whh) {
  int idx = blockIdx.x * 256 + threadIdx.x;   // 2048*1280 total
  int grow = idx / KCAT, kc = idx - grow * KCAT;
  float v;
  if (kc < 256) {
    v = Wih[(size_t)grow * EN + kc];
  } else if (kc < 768) {
    v = Whh[(size_t)grow * HN + (kc - 256)];
  } else {
    float f = Whh[(size_t)grow * HN + (kc - 768)];
    v = f - f_of_bf(bf_of(f));                // residual (lo) term
  }
  Wall[idx] = bf_of(v);
}

// ---------- flag poll (called by ONE wave per block) ----------
__device__ __forceinline__ void poll_flags(const unsigned* flags,
                                           unsigned want, int l) {
  bool done = false;
  while (true) {
    if (!done) {
      unsigned v = __hip_atomic_load(&flags[l], __ATOMIC_RELAXED, SCOPE);
      done = (v >= want);
    }
    if (__all(done ? 1 : 0)) break;
    __builtin_amdgcn_s_sleep(2);
  }
  asm volatile("" ::: "memory");   // no hoisting of subsequent loads above
}

// 16 pipelined IC loads (sc1) from 4 bases x offsets {0,1024,2048,3072}.
#define HLOAD16                                                             \
  asm volatile(                                                             \
    "global_load_dwordx4 %0,  %16, off sc1\n\t"                             \
    "global_load_dwordx4 %1,  %16, off offset:1024 sc1\n\t"                 \
    "global_load_dwordx4 %2,  %16, off offset:2048 sc1\n\t"                 \
    "global_load_dwordx4 %3,  %16, off offset:3072 sc1\n\t"                 \
    "global_load_dwordx4 %4,  %17, off sc1\n\t"                             \
    "global_load_dwordx4 %5,  %17, off offset:1024 sc1\n\t"                 \
    "global_load_dwordx4 %6,  %17, off offset:2048 sc1\n\t"                 \
    "global_load_dwordx4 %7,  %17, off offset:3072 sc1\n\t"                 \
    "global_load_dwordx4 %8,  %18, off sc1\n\t"                             \
    "global_load_dwordx4 %9,  %18, off offset:1024 sc1\n\t"                 \
    "global_load_dwordx4 %10, %18, off offset:2048 sc1\n\t"                 \
    "global_load_dwordx4 %11, %18, off offset:3072 sc1\n\t"                 \
    "global_load_dwordx4 %12, %19, off sc1\n\t"                             \
    "global_load_dwordx4 %13, %19, off offset:1024 sc1\n\t"                 \
    "global_load_dwordx4 %14, %19, off offset:2048 sc1\n\t"                 \
    "global_load_dwordx4 %15, %19, off offset:3072 sc1\n\t"                 \
    "s_waitcnt vmcnt(0)"                                                    \
    : "=&v"(hv0), "=&v"(hv1), "=&v"(hv2),  "=&v"(hv3),                      \
      "=&v"(hv4), "=&v"(hv5), "=&v"(hv6),  "=&v"(hv7),                      \
      "=&v"(hv8), "=&v"(hv9), "=&v"(hv10), "=&v"(hv11),                     \
      "=&v"(hv12), "=&v"(hv13), "=&v"(hv14), "=&v"(hv15)                    \
    : "v"(hb0), "v"(hb1), "v"(hb2), "v"(hb3) : "memory")

// ---------- scan: 64 blocks x 512 thr, block owns h-cols [8*blk, 8*blk+8) --
__global__ __launch_bounds__(512, 1) void scan_kernel(
    const short* __restrict__ weB, const short* __restrict__ Wall,
    char* __restrict__ hb, const int* __restrict__ length,
    const float* __restrict__ bih, const float* __restrict__ bhh,
    const float* __restrict__ Wcls, const float* __restrict__ bcls,
    float* __restrict__ part, unsigned* flags, float* __restrict__ out) {
  __shared__ float gl[32][65];            // gate rows r = type*8+jj, col b
  __shared__ __align__(16) short hstage[BN][8];
  const int tid = threadIdx.x;
  const int l = tid & 63, w = tid >> 6;
  const int bid = blockIdx.x;
  const int j0 = bid * 8;

  // --- MFMA role: wave w -> C rows [rhalf,+16), cols [btile,+16)
  const int btile = (w & 3) * 16;
  const int rhalf = (w >> 2) * 16;

  short8 aH[24], aL[16];
  {
    int r = rhalf + (l & 15);
    int grow = (r >> 3) * HN + j0 + (r & 7);
    const short* wp = Wall + (size_t)grow * KCAT + 8 * (l >> 4);
#pragma unroll
    for (int kk = 0; kk < 24; kk++) aH[kk] = *(const short8*)(wp + kk * 32);
#pragma unroll
    for (int kk = 0; kk < 16; kk++) aL[kk] = *(const short8*)(wp + 768 + kk * 32);
  }

  // --- elementwise role: thread -> (jj = w, b = l)
  const int jj = w, b = l;
  float bias[4];
#pragma unroll
  for (int ty = 0; ty < 4; ty++) {
    int grow = ty * HN + j0 + jj;
    bias[ty] = bih[grow] + bhh[grow];
  }
  const int len = length[b];
  float c = 0.f, fmx = -INFINITY;

  // consumer base within a slot: (l>>4)*16384 + sample*16
  const int cons_off = (l >> 4) * 16384 + (btile + (l & 15)) * 16;
  // producer store offset within a slot: (bid&3)*16384 + (bid>>2)*1024 + l*16
  const int prod_off = (bid & 3) * 16384 + (bid >> 2) * 1024 + l * 16;

  for (int t = 0; t < TN; t++) {
    // ---- x side: loads + MFMAs BEFORE the poll (no h dependency) ----
    const short* xrow = weB + ((size_t)(t * 64 + btile + (l & 15))) * EN + 8 * (l >> 4);
    short8 xf[8];
#pragma unroll
    for (int kk = 0; kk < 8; kk++) xf[kk] = *(const short8*)(xrow + kk * 32);
    f32x4 accH = {0.f, 0.f, 0.f, 0.f}, accL = {0.f, 0.f, 0.f, 0.f};
#pragma unroll
    for (int kk = 0; kk < 8; kk++)
      accH = MFMA(aH[kk], xf[kk], accH);

    // ---- wait: SINGLE wave polls ----
    if (w == 0) poll_flags(flags, (unsigned)t, l);
    __syncthreads();                      // (c) release block after poll

    // ---- h side: 16 pipelined IC loads, producer-major layout ----
    const char* hb0 = hb + (size_t)(t & 7) * SLOTB + cons_off;
    const char* hb1 = hb0 + 4096;
    const char* hb2 = hb0 + 8192;
    const char* hb3 = hb0 + 12288;
    short8 hv0, hv1, hv2, hv3, hv4, hv5, hv6, hv7;
    short8 hv8, hv9, hv10, hv11, hv12, hv13, hv14, hv15;
    HLOAD16;
    accH = MFMA(aH[8],  hv0,  accH);  accL = MFMA(aL[0],  hv0,  accL);
    accH = MFMA(aH[9],  hv1,  accH);  accL = MFMA(aL[1],  hv1,  accL);
    accH = MFMA(aH[10], hv2,  accH);  accL = MFMA(aL[2],  hv2,  accL);
    accH = MFMA(aH[11], hv3,  accH);  accL = MFMA(aL[3],  hv3,  accL);
    accH = MFMA(aH[12], hv4,  accH);  accL = MFMA(aL[4],  hv4,  accL);
    accH = MFMA(aH[13], hv5,  accH);  accL = MFMA(aL[5],  hv5,  accL);
    accH = MFMA(aH[14], hv6,  accH);  accL = MFMA(aL[6],  hv6,  accL);
    accH = MFMA(aH[15], hv7,  accH);  accL = MFMA(aL[7],  hv7,  accL);
    accH = MFMA(aH[16], hv8,  accH);  accL = MFMA(aL[8],  hv8,  accL);
    accH = MFMA(aH[17], hv9,  accH);  accL = MFMA(aL[9],  hv9,  accL);
    accH = MFMA(aH[18], hv10, accH);  accL = MFMA(aL[10], hv10, accL);
    accH = MFMA(aH[19], hv11, accH);  accL = MFMA(aL[11], hv11, accL);
    accH = MFMA(aH[20], hv12, accH);  accL = MFMA(aL[12], hv12, accL);
    accH = MFMA(aH[21], hv13, accH);  accL = MFMA(aL[13], hv13, accL);
    accH = MFMA(aH[22], hv14, accH);  accL = MFMA(aL[14], hv14, accL);
    accH = MFMA(aH[23], hv15, accH);  accL = MFMA(aL[15], hv15, accL);

#pragma unroll
    for (int q = 0; q < 4; q++) {         // C/D: col = lane&15, row = (lane>>4)*4+q
      int r = rhalf + (l >> 4) * 4 + q;
      gl[r][btile + (l & 15)] = accH[q] + accL[q];
    }
    __syncthreads();                      // (a) gates visible to nonlin threads
    {
      float gi = gl[0 + jj][b] + bias[0];
      float gf = gl[8 + jj][b] + bias[1];
      float gg = gl[16 + jj][b] + bias[2];
      float go = gl[24 + jj][b] + bias[3];
      float si = 1.f / (1.f + __expf(-gi));
      float sf = 1.f / (1.f + __expf(-gf));
      float so = 1.f / (1.f + __expf(-go));
      float tg = 2.f / (1.f + __expf(-2.f * gg)) - 1.f;
      c = sf * c + si * tg;
      float tc = 2.f / (1.f + __expf(-2.f * c)) - 1.f;
      float h = so * tc;
      hstage[b][jj] = bf_of(h);
      if (t < len) fmx = fmaxf(fmx, h);
    }
    __syncthreads();                      // (b) hstage complete
    if (w == 0) {                         // wave 0: ONE contiguous 16B store/lane
      short8 val = *(const short8*)&hstage[l][0];
      char* dp = hb + (size_t)((t + 1) & 7) * SLOTB + prod_off;
      asm volatile("global_store_dwordx4 %0, %1, off sc1"
                   :: "v"(dp), "v"(val) : "memory");
      asm volatile("s_waitcnt vmcnt(0)" ::: "memory");
      if (l == 0)
        __hip_atomic_store(&flags[bid], (unsigned)(t + 1),
                           __ATOMIC_RELAXED, SCOPE);
    }
    // WAR: slot (t+1)&7 clobbers h_{t-7}; poll(t) certified all blocks
    // published h_t => consumed h_{t-1} => consumed h_{t-7}. Safe.
  }

  // --- classifier partials ---
  gl[jj][b]      = fmx * Wcls[j0 + jj];
  gl[8 + jj][b]  = fmx * Wcls[HN + j0 + jj];
  __syncthreads();
  if (tid < 128) {
    int cls = tid >> 6, bb = tid & 63;
    float s = 0.f;
#pragma unroll
    for (int q = 0; q < 8; q++) s += gl[cls * 8 + q][bb];
    __hip_atomic_store(&part[(size_t)bid * 128 + cls * 64 + bb], s,
                       __ATOMIC_RELAXED, SCOPE);
  }
  __syncthreads();
  asm volatile("s_waitcnt vmcnt(0)" ::: "memory");
  if (tid == 0)
    __hip_atomic_store(&flags[bid], (unsigned)(TN + 1), __ATOMIC_RELAXED, SCOPE);
  if (bid == 0) {
    if (w == 0) poll_flags(flags, (unsigned)(TN + 1), l);
    __syncthreads();
    if (tid < 128) {
      int cls = tid >> 6, bb = tid & 63;
      float s = bcls[cls];
#pragma unroll 8
      for (int k = 0; k < NBLK; k++)
        s += __uint_as_float(__hip_atomic_load(
            (const unsigned*)&part[(size_t)k * 128 + cls * 64 + bb],
            __ATOMIC_RELAXED, SCOPE));
      out[bb * 2 + cls] = s;
    }
  }
}

extern "C" void kernel_launch(void* const* d_in, const int* in_sizes, int n_in,
                              void* d_out, int out_size, void* d_ws, size_t ws_size,
                              hipStream_t stream) {
  const int*   x    = (const int*)d_in[0];
  const int*   len  = (const int*)d_in[1];
  const float* emb  = (const float*)d_in[2];
  const float* Wih  = (const float*)d_in[3];
  const float* Whh  = (const float*)d_in[4];
  const float* bih  = (const float*)d_in[5];
  const float* bhh  = (const float*)d_in[6];
  const float* Wcls = (const float*)d_in[7];
  const float* bcls = (const float*)d_in[8];
  float* out = (float*)d_out;

  char* ws = (char*)d_ws;
  short* weB  = (short*)ws;                                   // 16,777,216 B
  short* Wall = (short*)(ws + 16777216ull);                   //  5,242,880 B
  char*  hb   = ws + 16777216ull + 5242880;                   // 8*64KB = 524,288 B
  float* part = (float*)(ws + 16777216ull + 5242880 + 524288);         // 32 KB
  unsigned* flagp = (unsigned*)(ws + 16777216ull + 5242880 + 524288 + 32768);

  zero_kernel<<<dim3(64), dim3(256), 0, stream>>>((unsigned*)hb, flagp);
  gather_kernel<<<dim3(TN), dim3(256), 0, stream>>>(weB, x, emb);
  prep_w_kernel<<<dim3((2048 * KCAT) / 256), dim3(256), 0, stream>>>(Wall, Wih, Whh);

  void* args[] = { (void*)&weB, (void*)&Wall, (void*)&hb, (void*)&len,
                   (void*)&bih, (void*)&bhh, (void*)&Wcls, (void*)&bcls,
                   (void*)&part, (void*)&flagp, (void*)&out };
  hipLaunchCooperativeKernel((void*)scan_kernel, dim3(NBLK), dim3(512),
                             args, 0, stream);
}